// Round 6
// baseline (287.497 us; speedup 1.0000x reference)
//
#include <hip/hip_runtime.h>
#include <math.h>

#define BB 8
#define CC 256
#define HH 256
#define WW 256
#define HWC (HH * WW)            // 65536 = 2^16 pixels per batch
#define G4  (HWC / 4)            // 16384 float4-groups per batch = 2^14

// native vector type: required by __builtin_nontemporal_* (HIP float4 class rejected)
typedef float nf4 __attribute__((ext_vector_type(4)));

// ---------------------------------------------------------------------------
// K1: channel mean+max. 2048 blocks x 256 threads = 32 waves/CU (full occ).
// Each block: 64 float4 pixel-groups x 4-way channel split (64 ch each),
// LDS combine. Reads 512 MiB (nt), writes 4 MiB of planes.
// ---------------------------------------------------------------------------
__global__ __launch_bounds__(256) void k_stats(const float* __restrict__ x,
                                               float* __restrict__ avgp,
                                               float* __restrict__ maxp) {
    __shared__ nf4 ssum[4][64];
    __shared__ nf4 smax[4][64];

    const int gi = threadIdx.x & 63;          // float4-group within block
    const int sp = threadIdx.x >> 6;          // channel split 0..3
    const int G  = blockIdx.x * 64 + gi;      // group over BB*G4 = 131072
    const int b  = G >> 14;
    const int p4 = G & (G4 - 1);

    const nf4* x4 = (const nf4*)x + (((size_t)(b * CC + sp * 64)) << 14) + p4;

    nf4 v = __builtin_nontemporal_load(x4);
    nf4 s = v, m = v;
#pragma unroll 8
    for (int c = 1; c < 64; ++c) {
        nf4 t = __builtin_nontemporal_load(x4 + ((size_t)c << 14));
        s += t;
        m.x = fmaxf(m.x, t.x); m.y = fmaxf(m.y, t.y);
        m.z = fmaxf(m.z, t.z); m.w = fmaxf(m.w, t.w);
    }
    ssum[sp][gi] = s;
    smax[sp][gi] = m;
    __syncthreads();

    if (threadIdx.x < 64) {
        nf4 s0 = ssum[0][threadIdx.x], s1 = ssum[1][threadIdx.x];
        nf4 s2 = ssum[2][threadIdx.x], s3 = ssum[3][threadIdx.x];
        nf4 m0 = smax[0][threadIdx.x], m1 = smax[1][threadIdx.x];
        nf4 m2 = smax[2][threadIdx.x], m3 = smax[3][threadIdx.x];
        nf4 sa = (s0 + s1) + (s2 + s3);
        const float inv = 1.0f / (float)CC;
        nf4 a = sa * inv;
        nf4 mm;
        mm.x = fmaxf(fmaxf(m0.x, m1.x), fmaxf(m2.x, m3.x));
        mm.y = fmaxf(fmaxf(m0.y, m1.y), fmaxf(m2.y, m3.y));
        mm.z = fmaxf(fmaxf(m0.z, m1.z), fmaxf(m2.z, m3.z));
        mm.w = fmaxf(fmaxf(m0.w, m1.w), fmaxf(m2.w, m3.w));
        int group = blockIdx.x * 64 + threadIdx.x;   // plane idx in float4 units
        ((nf4*)avgp)[group] = a;
        ((nf4*)maxp)[group] = mm;
    }
}

// ---------------------------------------------------------------------------
// K2: 7x7 conv (2->1, SAME) + bias + sigmoid. 4 outputs per thread (one
// float4 store). Per kh: load the 10-float span once per plane (predicated
// at borders), reuse across 7 kw taps x 4 outputs. 512 blocks.
// ---------------------------------------------------------------------------
__global__ __launch_bounds__(256) void k_conv(const float* __restrict__ avgp,
                                              const float* __restrict__ maxp,
                                              const float* __restrict__ cw,
                                              const float* __restrict__ cb,
                                              float* __restrict__ attnp) {
    // block covers 1024 consecutive pixels = 4 rows of one batch
    int pbase = blockIdx.x * 1024;                 // batch-flat pixel base
    int r  = threadIdx.x >> 6;                     // row within block 0..3
    int wq = threadIdx.x & 63;                     // float4-column 0..63
    int pix  = (pbase & (HWC - 1)) + (r << 8);     // pixel within batch
    int b    = pbase >> 16;
    int h    = pix >> 8;
    int w0   = wq << 2;                            // first output col

    const float* ap = avgp + ((size_t)b << 16);
    const float* mp = maxp + ((size_t)b << 16);

    float bias = cb[0];
    float acc0 = bias, acc1 = bias, acc2 = bias, acc3 = bias;

#pragma unroll
    for (int kh = 0; kh < 7; ++kh) {
        int hh = h + kh - 3;
        if ((unsigned)hh >= (unsigned)HH) continue;
        const float* arow = ap + (hh << 8);
        const float* mrow = mp + (hh << 8);
        float ea[10], em[10];
#pragma unroll
        for (int j = 0; j < 10; ++j) {
            int col = w0 + j - 3;
            bool ok = (unsigned)col < (unsigned)WW;
            ea[j] = ok ? arow[col] : 0.0f;
            em[j] = ok ? mrow[col] : 0.0f;
        }
#pragma unroll
        for (int kw = 0; kw < 7; ++kw) {
            float wa = cw[kh * 7 + kw];
            float wm = cw[49 + kh * 7 + kw];
            acc0 = fmaf(wa, ea[kw],     acc0); acc0 = fmaf(wm, em[kw],     acc0);
            acc1 = fmaf(wa, ea[kw + 1], acc1); acc1 = fmaf(wm, em[kw + 1], acc1);
            acc2 = fmaf(wa, ea[kw + 2], acc2); acc2 = fmaf(wm, em[kw + 2], acc2);
            acc3 = fmaf(wa, ea[kw + 3], acc3); acc3 = fmaf(wm, em[kw + 3], acc3);
        }
    }
    nf4 o;
    o.x = 1.0f / (1.0f + __expf(-acc0));
    o.y = 1.0f / (1.0f + __expf(-acc1));
    o.z = 1.0f / (1.0f + __expf(-acc2));
    o.w = 1.0f / (1.0f + __expf(-acc3));
    ((nf4*)attnp)[blockIdx.x * 256 + threadIdx.x] = o;
}

// ---------------------------------------------------------------------------
// K3: out = x * attn. Flat contiguous streaming: 8 float4 per thread at
// +256 float4 strides (block covers 32 KiB linear). attn is 2 MiB total ->
// per-XCD L2 resident; per-j attn loads are coalesced 1 KiB/wave L2 hits.
// 16384 blocks.
// ---------------------------------------------------------------------------
__global__ __launch_bounds__(256) void k_mul(const float* __restrict__ x,
                                             const float* __restrict__ attnp,
                                             float* __restrict__ out) {
    size_t g0 = (size_t)blockIdx.x * 2048 + threadIdx.x;  // float4 index
    const nf4* x4 = (const nf4*)x;
    const nf4* a4 = (const nf4*)attnp;
    nf4*       o4 = (nf4*)out;

    nf4 v[8], a[8];
#pragma unroll
    for (int j = 0; j < 8; ++j) {
        size_t g = g0 + (size_t)j * 256;
        int p4 = (int)(g & (size_t)(G4 - 1));             // pixel-quad in batch
        int b  = (int)(g >> 22);                          // g / (CC*G4)
        a[j] = a4[((size_t)b << 14) + p4];
        v[j] = __builtin_nontemporal_load(x4 + g);
    }
#pragma unroll
    for (int j = 0; j < 8; ++j) {
        __builtin_nontemporal_store(v[j] * a[j], o4 + g0 + (size_t)j * 256);
    }
}

extern "C" void kernel_launch(void* const* d_in, const int* in_sizes, int n_in,
                              void* d_out, int out_size, void* d_ws, size_t ws_size,
                              hipStream_t stream) {
    const float* x  = (const float*)d_in[0];
    const float* cw = (const float*)d_in[1];   // (1,2,7,7) = 98 floats
    const float* cb = (const float*)d_in[2];   // 1 float
    float* out = (float*)d_out;

    // workspace: avg | max | attn planes (BB*HWC floats each, 2 MiB each)
    float* avgp  = (float*)d_ws;
    float* maxp  = avgp + (size_t)BB * HWC;
    float* attnp = maxp + (size_t)BB * HWC;

    // K1: BB*G4 float4-groups, 64 per block, 4-way channel split -> 2048 blocks
    k_stats<<<BB * G4 / 64, 256, 0, stream>>>(x, avgp, maxp);
    // K2: 1024 pixels per block -> 512 blocks
    k_conv<<<BB * HWC / 1024, 256, 0, stream>>>(avgp, maxp, cw, cb, attnp);
    // K3: flat, 2048 float4 per block -> 16384 blocks
    k_mul<<<(BB * CC * G4) / 2048, 256, 0, stream>>>(x, attnp, out);
}

// Round 7
// 279.504 us; speedup vs baseline: 1.0286x; 1.0286x over previous
//
#include <hip/hip_runtime.h>
#include <math.h>

#define BB 8
#define CC 256
#define HH 256
#define WW 256
#define HWC (HH * WW)            // 65536 = 2^16 pixels per batch
#define G4  (HWC / 4)            // 16384 float4-groups per batch = 2^14

// native vector type: required by __builtin_nontemporal_* (HIP float4 class rejected)
typedef float nf4 __attribute__((ext_vector_type(4)));

// ---------------------------------------------------------------------------
// K1: channel mean+max. 2048 blocks x 256 threads = 32 waves/CU (full occ).
// Each block: 64 float4 pixel-groups x 4-way channel split (64 ch each),
// LDS combine. Reads 512 MiB (nt), writes 4 MiB of planes.
// ---------------------------------------------------------------------------
__global__ __launch_bounds__(256) void k_stats(const float* __restrict__ x,
                                               float* __restrict__ avgp,
                                               float* __restrict__ maxp) {
    __shared__ nf4 ssum[4][64];
    __shared__ nf4 smax[4][64];

    const int gi = threadIdx.x & 63;          // float4-group within block
    const int sp = threadIdx.x >> 6;          // channel split 0..3
    const int G  = blockIdx.x * 64 + gi;      // group over BB*G4 = 131072
    const int b  = G >> 14;
    const int p4 = G & (G4 - 1);

    const nf4* x4 = (const nf4*)x + (((size_t)(b * CC + sp * 64)) << 14) + p4;

    nf4 v = __builtin_nontemporal_load(x4);
    nf4 s = v, m = v;
#pragma unroll 8
    for (int c = 1; c < 64; ++c) {
        nf4 t = __builtin_nontemporal_load(x4 + ((size_t)c << 14));
        s += t;
        m.x = fmaxf(m.x, t.x); m.y = fmaxf(m.y, t.y);
        m.z = fmaxf(m.z, t.z); m.w = fmaxf(m.w, t.w);
    }
    ssum[sp][gi] = s;
    smax[sp][gi] = m;
    __syncthreads();

    if (threadIdx.x < 64) {
        nf4 s0 = ssum[0][threadIdx.x], s1 = ssum[1][threadIdx.x];
        nf4 s2 = ssum[2][threadIdx.x], s3 = ssum[3][threadIdx.x];
        nf4 m0 = smax[0][threadIdx.x], m1 = smax[1][threadIdx.x];
        nf4 m2 = smax[2][threadIdx.x], m3 = smax[3][threadIdx.x];
        nf4 sa = (s0 + s1) + (s2 + s3);
        const float inv = 1.0f / (float)CC;
        nf4 a = sa * inv;
        nf4 mm;
        mm.x = fmaxf(fmaxf(m0.x, m1.x), fmaxf(m2.x, m3.x));
        mm.y = fmaxf(fmaxf(m0.y, m1.y), fmaxf(m2.y, m3.y));
        mm.z = fmaxf(fmaxf(m0.z, m1.z), fmaxf(m2.z, m3.z));
        mm.w = fmaxf(fmaxf(m0.w, m1.w), fmaxf(m2.w, m3.w));
        int group = blockIdx.x * 64 + threadIdx.x;   // plane idx in float4 units
        ((nf4*)avgp)[group] = a;
        ((nf4*)maxp)[group] = mm;
    }
}

// ---------------------------------------------------------------------------
// K2: 7x7 conv (2->1, SAME) + bias + sigmoid. 4 outputs per thread (one
// float4 store). Per kh: load the 10-float span once per plane (predicated
// at borders), reuse across 7 kw taps x 4 outputs. 512 blocks.
// ---------------------------------------------------------------------------
__global__ __launch_bounds__(256) void k_conv(const float* __restrict__ avgp,
                                              const float* __restrict__ maxp,
                                              const float* __restrict__ cw,
                                              const float* __restrict__ cb,
                                              float* __restrict__ attnp) {
    // block covers 1024 consecutive pixels = 4 rows of one batch
    int pbase = blockIdx.x * 1024;                 // batch-flat pixel base
    int r  = threadIdx.x >> 6;                     // row within block 0..3
    int wq = threadIdx.x & 63;                     // float4-column 0..63
    int pix  = (pbase & (HWC - 1)) + (r << 8);     // pixel within batch
    int b    = pbase >> 16;
    int h    = pix >> 8;
    int w0   = wq << 2;                            // first output col

    const float* ap = avgp + ((size_t)b << 16);
    const float* mp = maxp + ((size_t)b << 16);

    float bias = cb[0];
    float acc0 = bias, acc1 = bias, acc2 = bias, acc3 = bias;

#pragma unroll
    for (int kh = 0; kh < 7; ++kh) {
        int hh = h + kh - 3;
        if ((unsigned)hh >= (unsigned)HH) continue;
        const float* arow = ap + (hh << 8);
        const float* mrow = mp + (hh << 8);
        float ea[10], em[10];
#pragma unroll
        for (int j = 0; j < 10; ++j) {
            int col = w0 + j - 3;
            bool ok = (unsigned)col < (unsigned)WW;
            ea[j] = ok ? arow[col] : 0.0f;
            em[j] = ok ? mrow[col] : 0.0f;
        }
#pragma unroll
        for (int kw = 0; kw < 7; ++kw) {
            float wa = cw[kh * 7 + kw];
            float wm = cw[49 + kh * 7 + kw];
            acc0 = fmaf(wa, ea[kw],     acc0); acc0 = fmaf(wm, em[kw],     acc0);
            acc1 = fmaf(wa, ea[kw + 1], acc1); acc1 = fmaf(wm, em[kw + 1], acc1);
            acc2 = fmaf(wa, ea[kw + 2], acc2); acc2 = fmaf(wm, em[kw + 2], acc2);
            acc3 = fmaf(wa, ea[kw + 3], acc3); acc3 = fmaf(wm, em[kw + 3], acc3);
        }
    }
    nf4 o;
    o.x = 1.0f / (1.0f + __expf(-acc0));
    o.y = 1.0f / (1.0f + __expf(-acc1));
    o.z = 1.0f / (1.0f + __expf(-acc2));
    o.w = 1.0f / (1.0f + __expf(-acc3));
    ((nf4*)attnp)[blockIdx.x * 256 + threadIdx.x] = o;
}

// ---------------------------------------------------------------------------
// K3: out = x * attn. 8 channels per thread (256 KiB-strided streams): attn
// loaded once per thread, 8 independent in-flight nt loads + nt stores.
// Measured best layout (R5: 279.8 us vs flat R6: 287.5 us). 16384 blocks.
// ---------------------------------------------------------------------------
__global__ __launch_bounds__(256) void k_mul(const float* __restrict__ x,
                                             const float* __restrict__ attnp,
                                             float* __restrict__ out) {
    size_t t = (size_t)blockIdx.x * 256 + threadIdx.x;  // over BB*(CC/8)*G4
    int p4 = (int)(t & (G4 - 1));
    int r  = (int)(t >> 14);
    int c8 = r & 31;                                    // channel-octet 0..31
    int b  = r >> 5;

    const nf4* x4 = (const nf4*)x;
    nf4*       o4 = (nf4*)out;
    size_t base = (((size_t)(b * CC + c8 * 8)) << 14) + p4;

    nf4 a = ((const nf4*)attnp)[((size_t)b << 14) + p4];

    nf4 v0 = __builtin_nontemporal_load(x4 + base + ((size_t)0 << 14));
    nf4 v1 = __builtin_nontemporal_load(x4 + base + ((size_t)1 << 14));
    nf4 v2 = __builtin_nontemporal_load(x4 + base + ((size_t)2 << 14));
    nf4 v3 = __builtin_nontemporal_load(x4 + base + ((size_t)3 << 14));
    nf4 v4 = __builtin_nontemporal_load(x4 + base + ((size_t)4 << 14));
    nf4 v5 = __builtin_nontemporal_load(x4 + base + ((size_t)5 << 14));
    nf4 v6 = __builtin_nontemporal_load(x4 + base + ((size_t)6 << 14));
    nf4 v7 = __builtin_nontemporal_load(x4 + base + ((size_t)7 << 14));

    __builtin_nontemporal_store(v0 * a, o4 + base + ((size_t)0 << 14));
    __builtin_nontemporal_store(v1 * a, o4 + base + ((size_t)1 << 14));
    __builtin_nontemporal_store(v2 * a, o4 + base + ((size_t)2 << 14));
    __builtin_nontemporal_store(v3 * a, o4 + base + ((size_t)3 << 14));
    __builtin_nontemporal_store(v4 * a, o4 + base + ((size_t)4 << 14));
    __builtin_nontemporal_store(v5 * a, o4 + base + ((size_t)5 << 14));
    __builtin_nontemporal_store(v6 * a, o4 + base + ((size_t)6 << 14));
    __builtin_nontemporal_store(v7 * a, o4 + base + ((size_t)7 << 14));
}

extern "C" void kernel_launch(void* const* d_in, const int* in_sizes, int n_in,
                              void* d_out, int out_size, void* d_ws, size_t ws_size,
                              hipStream_t stream) {
    const float* x  = (const float*)d_in[0];
    const float* cw = (const float*)d_in[1];   // (1,2,7,7) = 98 floats
    const float* cb = (const float*)d_in[2];   // 1 float
    float* out = (float*)d_out;

    // workspace: avg | max | attn planes (BB*HWC floats each, 2 MiB each)
    float* avgp  = (float*)d_ws;
    float* maxp  = avgp + (size_t)BB * HWC;
    float* attnp = maxp + (size_t)BB * HWC;

    // K1: BB*G4 float4-groups, 64 per block, 4-way channel split -> 2048 blocks
    k_stats<<<BB * G4 / 64, 256, 0, stream>>>(x, avgp, maxp);
    // K2: 1024 pixels per block -> 512 blocks
    k_conv<<<BB * HWC / 1024, 256, 0, stream>>>(avgp, maxp, cw, cb, attnp);
    // K3: BB*(CC/8)*G4 threads -> 16384 blocks
    k_mul<<<BB * (CC / 8) * G4 / 256, 256, 0, stream>>>(x, attnp, out);
}